// Round 2
// baseline (463.242 us; speedup 1.0000x reference)
//
#include <hip/hip_runtime.h>
#include <stdint.h>

#define N_NODES 8192
#define FEAT 512

// ---------- helpers ----------
__device__ __forceinline__ unsigned short f2bf(float f) {
  // round-to-nearest-even f32 -> bf16
  unsigned int u = __float_as_uint(f);
  u += 0x7fffu + ((u >> 16) & 1u);
  return (unsigned short)(u >> 16);
}
__device__ __forceinline__ float bflo(unsigned int u) { return __uint_as_float(u << 16); }
__device__ __forceinline__ float bfhi(unsigned int u) { return __uint_as_float(u & 0xffff0000u); }

typedef __attribute__((ext_vector_type(8))) short short8;
typedef __attribute__((ext_vector_type(4))) float floatx4;

// ---------- K0: transpose+convert W -> Wt[n][k] bf16, zero deg ----------
__global__ __launch_bounds__(256) void prep_kernel(const float* __restrict__ W,
                                                   unsigned short* __restrict__ Wt,
                                                   unsigned int* __restrict__ deg) {
  int gid = blockIdx.x * 256 + threadIdx.x;   // 0..262143, reads W[k][n] coalesced
  int k = gid >> 9, n = gid & 511;
  Wt[n * 512 + k] = f2bf(W[gid]);
  if (gid < N_NODES) deg[gid] = 0u;
}

// ---------- K1: hidden(bf16) = bf16(x) @ bf16(W) + b ----------
// block = 512 thr (8 waves), tile BM=64 x BN=256, BK=32, grid (128, 2)
// wave (wm in 0..1, wn in 0..3) computes 32x64 -> 2x4 frags of 16x16x32 MFMA
__global__ __launch_bounds__(512) void gemm_kernel(const float* __restrict__ x,
                                                   const unsigned short* __restrict__ Wt,
                                                   const float* __restrict__ bias,
                                                   unsigned short* __restrict__ hidden) {
  __shared__ __align__(16) unsigned short Ab[64][40];    // +8 pad: bank spread
  __shared__ __align__(16) unsigned short Bb[256][40];
  int t = threadIdx.x;
  int m0 = blockIdx.x * 64;
  int n0 = blockIdx.y * 256;
  int lane = t & 63, wave = t >> 6;
  int quad = lane >> 4, l15 = lane & 15;
  int wm = wave & 1, wn = wave >> 1;

  floatx4 acc[2][4];
#pragma unroll
  for (int i = 0; i < 2; ++i)
#pragma unroll
    for (int j = 0; j < 4; ++j) acc[i][j] = (floatx4)0.0f;

  int arow = t >> 3, ac = (t & 7) * 4;    // A stage: 64x32 fp32, 1 float4/thread (full tile)
  int brow = t >> 1, bc = (t & 1) * 16;   // B stage: 256x32 bf16, 2 uint4/thread (full tile)
  const float* xa = x + (size_t)(m0 + arow) * 512 + ac;
  const unsigned short* wb = Wt + (size_t)(n0 + brow) * 512 + bc;

  for (int kt = 0; kt < 16; ++kt) {
    int k0 = kt * 32;
    __syncthreads();
    float4 av = *(const float4*)(xa + k0);
    uint2 aw;
    aw.x = (unsigned int)f2bf(av.x) | ((unsigned int)f2bf(av.y) << 16);
    aw.y = (unsigned int)f2bf(av.z) | ((unsigned int)f2bf(av.w) << 16);
    *(uint2*)&Ab[arow][ac] = aw;
    uint4 bv0 = *(const uint4*)(wb + k0);       // 16 shorts/thread: full 256x32 tile
    uint4 bv1 = *(const uint4*)(wb + k0 + 8);
    *(uint4*)&Bb[brow][bc] = bv0;
    *(uint4*)&Bb[brow][bc + 8] = bv1;
    __syncthreads();

    short8 af[2];
    short8 bfr[4];
#pragma unroll
    for (int im = 0; im < 2; ++im)
      af[im] = *(const short8*)&Ab[wm * 32 + im * 16 + l15][quad * 8];
#pragma unroll
    for (int jn = 0; jn < 4; ++jn)
      bfr[jn] = *(const short8*)&Bb[wn * 64 + jn * 16 + l15][quad * 8];
#pragma unroll
    for (int im = 0; im < 2; ++im)
#pragma unroll
      for (int jn = 0; jn < 4; ++jn)
        acc[im][jn] = __builtin_amdgcn_mfma_f32_16x16x32_bf16(af[im], bfr[jn], acc[im][jn], 0, 0, 0);
  }

  // epilogue: C/D layout col=lane&15, row=quad*4+reg (m89-verified)
#pragma unroll
  for (int jn = 0; jn < 4; ++jn) {
    int col = n0 + wn * 64 + jn * 16 + l15;
    float bb = bias[col];
#pragma unroll
    for (int im = 0; im < 2; ++im) {
#pragma unroll
      for (int rg = 0; rg < 4; ++rg) {
        int row = m0 + wm * 32 + im * 16 + quad * 4 + rg;
        hidden[(size_t)row * 512 + col] = f2bf(acc[im][jn][rg] + bb);
      }
    }
  }
}

// ---------- K2: out(unnorm) = A @ hidden ; deg column counts ----------
// 1024 blocks x 256 thr (4 waves); 8 rows/block, 2 rows/wave; 32 KB LDS deg counters
#define PROC(val, e)                                                        \
  {                                                                         \
    bool nz = ((val) != 0.0f);                                              \
    if (nz) atomicAdd(&degl[base + 4 * lane + (e)], 1u);                    \
    unsigned long long m = __ballot(nz);                                    \
    while (m) {                                                             \
      int bit = __builtin_ctzll(m);                                         \
      m &= (m - 1);                                                         \
      int j = base + 4 * bit + (e);                                         \
      const uint2* hp = (const uint2*)(hidden + ((size_t)j << 9));          \
      uint2 h0 = hp[lane];                                                  \
      uint2 h1 = hp[64 + lane];                                             \
      acc[0] += bflo(h0.x); acc[1] += bfhi(h0.x);                           \
      acc[2] += bflo(h0.y); acc[3] += bfhi(h0.y);                           \
      acc[4] += bflo(h1.x); acc[5] += bfhi(h1.x);                           \
      acc[6] += bflo(h1.y); acc[7] += bfhi(h1.y);                           \
    }                                                                       \
  }

__global__ __launch_bounds__(256) void gather_kernel(const float* __restrict__ adj,
                                                     const unsigned short* __restrict__ hidden,
                                                     float* __restrict__ out,
                                                     unsigned int* __restrict__ deg) {
  __shared__ unsigned int degl[N_NODES];
  int tid = threadIdx.x;
#pragma unroll
  for (int i = 0; i < 32; ++i) degl[i * 256 + tid] = 0u;
  __syncthreads();

  int lane = tid & 63, wave = tid >> 6;
  int rbase = blockIdx.x * 8 + wave * 2;
  for (int rr = 0; rr < 2; ++rr) {
    int r = rbase + rr;
    const float4* __restrict__ arow = (const float4*)(adj + ((size_t)r << 13));
    float acc[8] = {0.f, 0.f, 0.f, 0.f, 0.f, 0.f, 0.f, 0.f};
    float4 cur = arow[lane];                      // chunk 0: cols 4*lane..4*lane+3
    for (int ch = 0; ch < 32; ++ch) {
      float4 nxt = make_float4(0.f, 0.f, 0.f, 0.f);
      if (ch < 31) nxt = arow[(ch + 1) * 64 + lane];   // prefetch next 256-col chunk
      int base = ch * 256;
      PROC(cur.x, 0)
      PROC(cur.y, 1)
      PROC(cur.z, 2)
      PROC(cur.w, 3)
      cur = nxt;
    }
    // lane owns features [4l..4l+3] and [256+4l..256+4l+3] -> coalesced float4 stores
    float4* orow = (float4*)(out + ((size_t)r << 9));
    orow[lane] = make_float4(acc[0], acc[1], acc[2], acc[3]);
    orow[64 + lane] = make_float4(acc[4], acc[5], acc[6], acc[7]);
  }
  __syncthreads();
#pragma unroll
  for (int i = 0; i < 32; ++i) {
    unsigned int c = degl[i * 256 + tid];
    if (c) atomicAdd(&deg[i * 256 + tid], c);     // sparse predicated global atomics
  }
}

// ---------- K3: out[r][:] /= deg[r] ----------
__global__ __launch_bounds__(256) void norm_kernel(float* __restrict__ out,
                                                   const unsigned int* __restrict__ deg) {
  int lane = threadIdx.x & 63, wave = threadIdx.x >> 6;
  int r = blockIdx.x * 4 + wave;
  float s = 1.0f / (float)deg[r];                 // deg>=1 (self-loop)
  float4* p = (float4*)(out + ((size_t)r << 9));
  float4 v0 = p[lane], v1 = p[64 + lane];
  v0.x *= s; v0.y *= s; v0.z *= s; v0.w *= s;
  v1.x *= s; v1.y *= s; v1.z *= s; v1.w *= s;
  p[lane] = v0;
  p[64 + lane] = v1;
}

extern "C" void kernel_launch(void* const* d_in, const int* in_sizes, int n_in,
                              void* d_out, int out_size, void* d_ws, size_t ws_size,
                              hipStream_t stream) {
  const float* x   = (const float*)d_in[0];   // [8192,512]
  const float* adj = (const float*)d_in[1];   // [8192,8192]
  const float* W   = (const float*)d_in[2];   // [512,512]
  const float* b   = (const float*)d_in[3];   // [512]
  float* out = (float*)d_out;

  char* ws = (char*)d_ws;
  unsigned short* hidden = (unsigned short*)ws;                               // 8 MiB bf16
  unsigned short* Wt     = (unsigned short*)(ws + (size_t)N_NODES * FEAT * 2);// 512 KiB
  unsigned int*   deg    = (unsigned int*)(ws + (size_t)N_NODES * FEAT * 2 + (size_t)FEAT * FEAT * 2);

  prep_kernel<<<1024, 256, 0, stream>>>(W, Wt, deg);
  gemm_kernel<<<dim3(128, 2), 512, 0, stream>>>(x, Wt, b, hidden);
  gather_kernel<<<1024, 256, 0, stream>>>(adj, hidden, out, deg);
  norm_kernel<<<2048, 256, 0, stream>>>(out, deg);
}

// Round 3
// 447.981 us; speedup vs baseline: 1.0341x; 1.0341x over previous
//
#include <hip/hip_runtime.h>
#include <stdint.h>

#define N_NODES 8192
#define FEAT 512
#define QCAP 1024   // per-wave gather queue (ushort indices); mean nnz/row ~83

// ---------- helpers ----------
__device__ __forceinline__ unsigned short f2bf(float f) {
  // round-to-nearest-even f32 -> bf16
  unsigned int u = __float_as_uint(f);
  u += 0x7fffu + ((u >> 16) & 1u);
  return (unsigned short)(u >> 16);
}
__device__ __forceinline__ float bflo(unsigned int u) { return __uint_as_float(u << 16); }
__device__ __forceinline__ float bfhi(unsigned int u) { return __uint_as_float(u & 0xffff0000u); }

typedef __attribute__((ext_vector_type(8))) short short8;
typedef __attribute__((ext_vector_type(4))) float floatx4;

// ---------- K0: transpose+convert W -> Wt[n][k] bf16, zero deg ----------
__global__ __launch_bounds__(256) void prep_kernel(const float* __restrict__ W,
                                                   unsigned short* __restrict__ Wt,
                                                   unsigned int* __restrict__ deg) {
  int gid = blockIdx.x * 256 + threadIdx.x;   // 0..262143, reads W[k][n] coalesced
  int k = gid >> 9, n = gid & 511;
  Wt[n * 512 + k] = f2bf(W[gid]);
  if (gid < N_NODES) deg[gid] = 0u;
}

// ---------- K1: hidden(bf16) = bf16(x) @ bf16(W) + b ----------
// block = 512 thr (8 waves), tile BM=64 x BN=256, BK=32, grid (128, 2)
__global__ __launch_bounds__(512) void gemm_kernel(const float* __restrict__ x,
                                                   const unsigned short* __restrict__ Wt,
                                                   const float* __restrict__ bias,
                                                   unsigned short* __restrict__ hidden) {
  __shared__ __align__(16) unsigned short Ab[64][40];
  __shared__ __align__(16) unsigned short Bb[256][40];
  int t = threadIdx.x;
  int m0 = blockIdx.x * 64;
  int n0 = blockIdx.y * 256;
  int lane = t & 63, wave = t >> 6;
  int quad = lane >> 4, l15 = lane & 15;
  int wm = wave & 1, wn = wave >> 1;

  floatx4 acc[2][4];
#pragma unroll
  for (int i = 0; i < 2; ++i)
#pragma unroll
    for (int j = 0; j < 4; ++j) acc[i][j] = (floatx4)0.0f;

  int arow = t >> 3, ac = (t & 7) * 4;    // A: 64x32 fp32, 1 float4/thread
  int brow = t >> 1, bc = (t & 1) * 16;   // B: 256x32 bf16, 2 uint4/thread
  const float* xa = x + (size_t)(m0 + arow) * 512 + ac;
  const unsigned short* wb = Wt + (size_t)(n0 + brow) * 512 + bc;

  for (int kt = 0; kt < 16; ++kt) {
    int k0 = kt * 32;
    __syncthreads();
    float4 av = *(const float4*)(xa + k0);
    uint2 aw;
    aw.x = (unsigned int)f2bf(av.x) | ((unsigned int)f2bf(av.y) << 16);
    aw.y = (unsigned int)f2bf(av.z) | ((unsigned int)f2bf(av.w) << 16);
    *(uint2*)&Ab[arow][ac] = aw;
    uint4 bv0 = *(const uint4*)(wb + k0);
    uint4 bv1 = *(const uint4*)(wb + k0 + 8);
    *(uint4*)&Bb[brow][bc] = bv0;
    *(uint4*)&Bb[brow][bc + 8] = bv1;
    __syncthreads();

    short8 af[2];
    short8 bfr[4];
#pragma unroll
    for (int im = 0; im < 2; ++im)
      af[im] = *(const short8*)&Ab[wm * 32 + im * 16 + l15][quad * 8];
#pragma unroll
    for (int jn = 0; jn < 4; ++jn)
      bfr[jn] = *(const short8*)&Bb[wn * 64 + jn * 16 + l15][quad * 8];
#pragma unroll
    for (int im = 0; im < 2; ++im)
#pragma unroll
      for (int jn = 0; jn < 4; ++jn)
        acc[im][jn] = __builtin_amdgcn_mfma_f32_16x16x32_bf16(af[im], bfr[jn], acc[im][jn], 0, 0, 0);
  }

  // epilogue: C/D layout col=lane&15, row=quad*4+reg (m89-verified)
#pragma unroll
  for (int jn = 0; jn < 4; ++jn) {
    int col = n0 + wn * 64 + jn * 16 + l15;
    float bb = bias[col];
#pragma unroll
    for (int im = 0; im < 2; ++im) {
#pragma unroll
      for (int rg = 0; rg < 4; ++rg) {
        int row = m0 + wm * 32 + im * 16 + quad * 4 + rg;
        hidden[(size_t)row * 512 + col] = f2bf(acc[im][jn][rg] + bb);
      }
    }
  }
}

// ---------- K2: out(unnorm) = A @ hidden ; deg column counts ----------
// scan row -> per-wave LDS index queue -> drain in blocks of 8 (16 loads in flight)
__global__ __launch_bounds__(256) void gather_kernel(const float* __restrict__ adj,
                                                     const unsigned short* __restrict__ hidden,
                                                     float* __restrict__ out,
                                                     unsigned int* __restrict__ deg) {
  __shared__ unsigned int degl[N_NODES];         // 32 KB column-degree counters
  __shared__ unsigned short q[4][QCAP];          // 8 KB per-wave gather queues
  int tid = threadIdx.x;
#pragma unroll
  for (int i = 0; i < 32; ++i) degl[i * 256 + tid] = 0u;
  __syncthreads();

  int lane = tid & 63, wave = tid >> 6;
  unsigned short* wq = q[wave];
  unsigned long long lanemask = (1ull << lane) - 1ull;
  int rbase = blockIdx.x * 8 + wave * 2;

  for (int rr = 0; rr < 2; ++rr) {
    int r = rbase + rr;
    const float4* __restrict__ arow = (const float4*)(adj + ((size_t)r << 13));
    float acc[8] = {0.f, 0.f, 0.f, 0.f, 0.f, 0.f, 0.f, 0.f};
    int qcnt = 0;

    auto drain = [&](int cnt) {
      int i = 0;
      for (; i + 8 <= cnt; i += 8) {
        int jj[8];
#pragma unroll
        for (int d = 0; d < 8; ++d) jj[d] = wq[i + d];   // wave-uniform LDS broadcast
        uint2 h0[8], h1[8];
#pragma unroll
        for (int d = 0; d < 8; ++d) {                    // 16 independent loads in flight
          const uint2* hp = (const uint2*)(hidden + ((size_t)jj[d] << 9));
          h0[d] = hp[lane];
          h1[d] = hp[64 + lane];
        }
#pragma unroll
        for (int d = 0; d < 8; ++d) {
          acc[0] += bflo(h0[d].x); acc[1] += bfhi(h0[d].x);
          acc[2] += bflo(h0[d].y); acc[3] += bfhi(h0[d].y);
          acc[4] += bflo(h1[d].x); acc[5] += bfhi(h1[d].x);
          acc[6] += bflo(h1[d].y); acc[7] += bfhi(h1[d].y);
        }
      }
      for (; i < cnt; ++i) {
        int j = wq[i];
        const uint2* hp = (const uint2*)(hidden + ((size_t)j << 9));
        uint2 h0 = hp[lane], h1 = hp[64 + lane];
        acc[0] += bflo(h0.x); acc[1] += bfhi(h0.x);
        acc[2] += bflo(h0.y); acc[3] += bfhi(h0.y);
        acc[4] += bflo(h1.x); acc[5] += bfhi(h1.x);
        acc[6] += bflo(h1.y); acc[7] += bfhi(h1.y);
      }
    };

    // ---- scan: build queue of nonzero column indices ----
    float4 cur = arow[lane];
    for (int ch = 0; ch < 32; ++ch) {
      float4 nxt = make_float4(0.f, 0.f, 0.f, 0.f);
      if (ch < 31) nxt = arow[(ch + 1) * 64 + lane];     // depth-2 prefetch
      if (qcnt > QCAP - 256) { drain(qcnt); qcnt = 0; }  // overflow guard (never in practice)
      int cbase = ch * 256 + 4 * lane;
#pragma unroll
      for (int e = 0; e < 4; ++e) {
        float val = (e == 0) ? cur.x : (e == 1) ? cur.y : (e == 2) ? cur.z : cur.w;
        bool nz = (val != 0.0f);
        unsigned long long m = __ballot(nz);
        if (nz) {
          atomicAdd(&degl[cbase + e], 1u);
          wq[qcnt + __popcll(m & lanemask)] = (unsigned short)(cbase + e);
        }
        qcnt += __popcll(m);                              // wave-uniform
      }
      cur = nxt;
    }

    // ---- drain remaining queue ----
    drain(qcnt);

    // lane owns features [4l..4l+3] and [256+4l..256+4l+3] -> coalesced float4 stores
    float4* orow = (float4*)(out + ((size_t)r << 9));
    orow[lane] = make_float4(acc[0], acc[1], acc[2], acc[3]);
    orow[64 + lane] = make_float4(acc[4], acc[5], acc[6], acc[7]);
  }

  __syncthreads();
#pragma unroll
  for (int i = 0; i < 32; ++i) {
    unsigned int c = degl[i * 256 + tid];
    if (c) atomicAdd(&deg[i * 256 + tid], c);             // sparse predicated global atomics
  }
}

// ---------- K3: out[r][:] /= deg[r] ----------
__global__ __launch_bounds__(256) void norm_kernel(float* __restrict__ out,
                                                   const unsigned int* __restrict__ deg) {
  int lane = threadIdx.x & 63, wave = threadIdx.x >> 6;
  int r = blockIdx.x * 4 + wave;
  float s = 1.0f / (float)deg[r];                         // deg>=1 (self-loop)
  float4* p = (float4*)(out + ((size_t)r << 9));
  float4 v0 = p[lane], v1 = p[64 + lane];
  v0.x *= s; v0.y *= s; v0.z *= s; v0.w *= s;
  v1.x *= s; v1.y *= s; v1.z *= s; v1.w *= s;
  p[lane] = v0;
  p[64 + lane] = v1;
}

extern "C" void kernel_launch(void* const* d_in, const int* in_sizes, int n_in,
                              void* d_out, int out_size, void* d_ws, size_t ws_size,
                              hipStream_t stream) {
  const float* x   = (const float*)d_in[0];   // [8192,512]
  const float* adj = (const float*)d_in[1];   // [8192,8192]
  const float* W   = (const float*)d_in[2];   // [512,512]
  const float* b   = (const float*)d_in[3];   // [512]
  float* out = (float*)d_out;

  char* ws = (char*)d_ws;
  unsigned short* hidden = (unsigned short*)ws;                               // 8 MiB bf16
  unsigned short* Wt     = (unsigned short*)(ws + (size_t)N_NODES * FEAT * 2);// 512 KiB
  unsigned int*   deg    = (unsigned int*)(ws + (size_t)N_NODES * FEAT * 2 + (size_t)FEAT * FEAT * 2);

  prep_kernel<<<1024, 256, 0, stream>>>(W, Wt, deg);
  gemm_kernel<<<dim3(128, 2), 512, 0, stream>>>(x, Wt, b, hidden);
  gather_kernel<<<1024, 256, 0, stream>>>(adj, hidden, out, deg);
  norm_kernel<<<2048, 256, 0, stream>>>(out, deg);
}

// Round 4
// 427.184 us; speedup vs baseline: 1.0844x; 1.0487x over previous
//
#include <hip/hip_runtime.h>
#include <stdint.h>

#define N_NODES 8192
#define FEAT 512
#define QCAP 512          // per-wave queue; inline drain keeps backlog < 300; wrap-indexed

// ---------- helpers ----------
__device__ __forceinline__ unsigned short f2bf(float f) {
  unsigned int u = __float_as_uint(f);
  u += 0x7fffu + ((u >> 16) & 1u);
  return (unsigned short)(u >> 16);
}
__device__ __forceinline__ float bflo(unsigned int u) { return __uint_as_float(u << 16); }
__device__ __forceinline__ float bfhi(unsigned int u) { return __uint_as_float(u & 0xffff0000u); }

typedef __attribute__((ext_vector_type(8))) short short8;
typedef __attribute__((ext_vector_type(4))) float floatx4;

// ---------- K0: transpose+convert W -> Wt[n][k] bf16, zero deg ----------
__global__ __launch_bounds__(256) void prep_kernel(const float* __restrict__ W,
                                                   unsigned short* __restrict__ Wt,
                                                   unsigned int* __restrict__ deg) {
  int gid = blockIdx.x * 256 + threadIdx.x;
  int k = gid >> 9, n = gid & 511;
  Wt[n * 512 + k] = f2bf(W[gid]);
  if (gid < N_NODES) deg[gid] = 0u;
}

// ---------- K1: hidden(bf16) = bf16(x) @ bf16(W) + b ----------
__global__ __launch_bounds__(512) void gemm_kernel(const float* __restrict__ x,
                                                   const unsigned short* __restrict__ Wt,
                                                   const float* __restrict__ bias,
                                                   unsigned short* __restrict__ hidden) {
  __shared__ __align__(16) unsigned short Ab[64][40];
  __shared__ __align__(16) unsigned short Bb[256][40];
  int t = threadIdx.x;
  int m0 = blockIdx.x * 64;
  int n0 = blockIdx.y * 256;
  int lane = t & 63, wave = t >> 6;
  int quad = lane >> 4, l15 = lane & 15;
  int wm = wave & 1, wn = wave >> 1;

  floatx4 acc[2][4];
#pragma unroll
  for (int i = 0; i < 2; ++i)
#pragma unroll
    for (int j = 0; j < 4; ++j) acc[i][j] = (floatx4)0.0f;

  int arow = t >> 3, ac = (t & 7) * 4;
  int brow = t >> 1, bc = (t & 1) * 16;
  const float* xa = x + (size_t)(m0 + arow) * 512 + ac;
  const unsigned short* wb = Wt + (size_t)(n0 + brow) * 512 + bc;

  for (int kt = 0; kt < 16; ++kt) {
    int k0 = kt * 32;
    __syncthreads();
    float4 av = *(const float4*)(xa + k0);
    uint2 aw;
    aw.x = (unsigned int)f2bf(av.x) | ((unsigned int)f2bf(av.y) << 16);
    aw.y = (unsigned int)f2bf(av.z) | ((unsigned int)f2bf(av.w) << 16);
    *(uint2*)&Ab[arow][ac] = aw;
    uint4 bv0 = *(const uint4*)(wb + k0);
    uint4 bv1 = *(const uint4*)(wb + k0 + 8);
    *(uint4*)&Bb[brow][bc] = bv0;
    *(uint4*)&Bb[brow][bc + 8] = bv1;
    __syncthreads();

    short8 af[2];
    short8 bfr[4];
#pragma unroll
    for (int im = 0; im < 2; ++im)
      af[im] = *(const short8*)&Ab[wm * 32 + im * 16 + l15][quad * 8];
#pragma unroll
    for (int jn = 0; jn < 4; ++jn)
      bfr[jn] = *(const short8*)&Bb[wn * 64 + jn * 16 + l15][quad * 8];
#pragma unroll
    for (int im = 0; im < 2; ++im)
#pragma unroll
      for (int jn = 0; jn < 4; ++jn)
        acc[im][jn] = __builtin_amdgcn_mfma_f32_16x16x32_bf16(af[im], bfr[jn], acc[im][jn], 0, 0, 0);
  }

#pragma unroll
  for (int jn = 0; jn < 4; ++jn) {
    int col = n0 + wn * 64 + jn * 16 + l15;
    float bb = bias[col];
#pragma unroll
    for (int im = 0; im < 2; ++im) {
#pragma unroll
      for (int rg = 0; rg < 4; ++rg) {
        int row = m0 + wm * 32 + im * 16 + quad * 4 + rg;
        hidden[(size_t)row * 512 + col] = f2bf(acc[im][jn][rg] + bb);
      }
    }
  }
}

// ---------- K2: out(unnorm) = A @ hidden ; deg column counts ----------
// 1024 blocks x 512 thr (8 waves); 1 row/wave; depth-2 adj prefetch;
// inline batch-of-8 uint4 gather drains overlapping the adj stream.
__global__ __launch_bounds__(512) void gather_kernel(const float* __restrict__ adj,
                                                     const unsigned short* __restrict__ hidden,
                                                     float* __restrict__ out,
                                                     unsigned int* __restrict__ deg) {
  __shared__ unsigned int degl[N_NODES];          // 32 KB column-degree counters
  __shared__ unsigned short q[8][QCAP];           // 8 KB per-wave gather queues
  int tid = threadIdx.x;
#pragma unroll
  for (int i = 0; i < 16; ++i) degl[i * 512 + tid] = 0u;
  __syncthreads();

  int lane = tid & 63, wave = tid >> 6;
  unsigned short* wq = q[wave];
  unsigned long long lanemask = (1ull << lane) - 1ull;
  int r = blockIdx.x * 8 + wave;

  const float4* __restrict__ arow = (const float4*)(adj + ((size_t)r << 13));
  float acc[8] = {0.f, 0.f, 0.f, 0.f, 0.f, 0.f, 0.f, 0.f};
  int qcnt = 0, qhead = 0;

  float4 c0 = arow[lane];                 // chunk 0
  float4 c1 = arow[64 + lane];            // chunk 1
  for (int ch = 0; ch < 32; ++ch) {
    float4 nx = make_float4(0.f, 0.f, 0.f, 0.f);
    if (ch < 30) nx = arow[(ch + 2) * 64 + lane];        // depth-2 prefetch
    int cbase = ch * 256 + 4 * lane;
#pragma unroll
    for (int e = 0; e < 4; ++e) {
      float val = (e == 0) ? c0.x : (e == 1) ? c0.y : (e == 2) ? c0.z : c0.w;
      bool nz = (val != 0.0f);
      unsigned long long m = __ballot(nz);
      if (nz) {
        atomicAdd(&degl[cbase + e], 1u);
        wq[(qcnt + __popcll(m & lanemask)) & (QCAP - 1)] = (unsigned short)(cbase + e);
      }
      qcnt += __popcll(m);                               // wave-uniform
    }
    c0 = c1; c1 = nx;
    // inline drain: 8 gathers in flight while the adj prefetch streams
    while (qcnt - qhead >= 8) {
      int jj[8];
#pragma unroll
      for (int d = 0; d < 8; ++d) jj[d] = wq[(qhead + d) & (QCAP - 1)];  // LDS broadcast
      uint4 h[8];
#pragma unroll
      for (int d = 0; d < 8; ++d)
        h[d] = ((const uint4*)(hidden + ((size_t)jj[d] << 9)))[lane];    // 8 dwordx4 in flight
#pragma unroll
      for (int d = 0; d < 8; ++d) {
        acc[0] += bflo(h[d].x); acc[1] += bfhi(h[d].x);
        acc[2] += bflo(h[d].y); acc[3] += bfhi(h[d].y);
        acc[4] += bflo(h[d].z); acc[5] += bfhi(h[d].z);
        acc[6] += bflo(h[d].w); acc[7] += bfhi(h[d].w);
      }
      qhead += 8;
    }
  }
  // leftover (< 8)
  for (; qhead < qcnt; ++qhead) {
    int j = wq[qhead & (QCAP - 1)];
    uint4 h = ((const uint4*)(hidden + ((size_t)j << 9)))[lane];
    acc[0] += bflo(h.x); acc[1] += bfhi(h.x);
    acc[2] += bflo(h.y); acc[3] += bfhi(h.y);
    acc[4] += bflo(h.z); acc[5] += bfhi(h.z);
    acc[6] += bflo(h.w); acc[7] += bfhi(h.w);
  }

  // lane owns features [8l..8l+7] -> two float4 stores
  float4* orow = (float4*)(out + ((size_t)r << 9));
  orow[2 * lane]     = make_float4(acc[0], acc[1], acc[2], acc[3]);
  orow[2 * lane + 1] = make_float4(acc[4], acc[5], acc[6], acc[7]);

  __syncthreads();
#pragma unroll
  for (int i = 0; i < 16; ++i) {
    unsigned int c = degl[i * 512 + tid];
    if (c) atomicAdd(&deg[i * 512 + tid], c);            // sparse predicated global atomics
  }
}

// ---------- K3: out[r][:] /= deg[r] ----------
__global__ __launch_bounds__(256) void norm_kernel(float* __restrict__ out,
                                                   const unsigned int* __restrict__ deg) {
  int lane = threadIdx.x & 63, wave = threadIdx.x >> 6;
  int r = blockIdx.x * 4 + wave;
  float s = 1.0f / (float)deg[r];                        // deg>=1 (self-loop)
  float4* p = (float4*)(out + ((size_t)r << 9));
  float4 v0 = p[lane], v1 = p[64 + lane];
  v0.x *= s; v0.y *= s; v0.z *= s; v0.w *= s;
  v1.x *= s; v1.y *= s; v1.z *= s; v1.w *= s;
  p[lane] = v0;
  p[64 + lane] = v1;
}

extern "C" void kernel_launch(void* const* d_in, const int* in_sizes, int n_in,
                              void* d_out, int out_size, void* d_ws, size_t ws_size,
                              hipStream_t stream) {
  const float* x   = (const float*)d_in[0];   // [8192,512]
  const float* adj = (const float*)d_in[1];   // [8192,8192]
  const float* W   = (const float*)d_in[2];   // [512,512]
  const float* b   = (const float*)d_in[3];   // [512]
  float* out = (float*)d_out;

  char* ws = (char*)d_ws;
  unsigned short* hidden = (unsigned short*)ws;                               // 8 MiB bf16
  unsigned short* Wt     = (unsigned short*)(ws + (size_t)N_NODES * FEAT * 2);// 512 KiB
  unsigned int*   deg    = (unsigned int*)(ws + (size_t)N_NODES * FEAT * 2 + (size_t)FEAT * FEAT * 2);

  prep_kernel<<<1024, 256, 0, stream>>>(W, Wt, deg);
  gemm_kernel<<<dim3(128, 2), 512, 0, stream>>>(x, Wt, b, hidden);
  gather_kernel<<<1024, 512, 0, stream>>>(adj, hidden, out, deg);
  norm_kernel<<<2048, 256, 0, stream>>>(out, deg);
}